// Round 9
// baseline (8017.300 us; speedup 1.0000x reference)
//
#include <hip/hip_runtime.h>
#include <math.h>

#define BB 64      // batch
#define SS 512     // seq len
#define EE 128     // embed dim
#define HH 256     // hidden
#define NC 9       // classes
#define G4 1024    // 4*H gates (one direction)
#define TCLOG 7
#define TC 128     // time chunk
#define NCH (SS / TC)

#define KV 14      // k4 chunks pinned in VGPR (56 regs; machinery ~64; cap 128)
#define KL 9       // k4 chunks cached in LDS = 144 KB
// streamed: k4 in [KV+KL, 64) = 41 chunks = 656 KB/step

// ---------- activations (overflow-safe, fast) ----------
__device__ __forceinline__ float sigf(float x) {
    return 1.0f / (1.0f + __expf(-x));
}
__device__ __forceinline__ float tanhfast(float x) {
    float a = fabsf(x);
    float e = __expf(-2.0f * a);
    float t = (1.0f - e) / (1.0f + e);
    return copysignf(t, x);
}
__device__ __forceinline__ float dot4(float4 w, float4 h, float a) {
    a = fmaf(w.x, h.x, a); a = fmaf(w.y, h.y, a);
    a = fmaf(w.z, h.z, a); a = fmaf(w.w, h.w, a);
    return a;
}

// ---------- transpose w_hh -> wT[dir][k4][j][4] ----------
__global__ void transpose_whh(const float* __restrict__ whh, float* __restrict__ wT) {
    // whh: [2][1024][256] ; wT: [2][64][1024][4]
    int idx = blockIdx.x * 256 + threadIdx.x;
    if (idx >= 2 * 64 * 1024) return;
    int jj  = idx & 1023;
    int k4  = (idx >> 10) & 63;
    int dir = idx >> 16;
    float4 v = *(const float4*)(whh + ((long)(dir * 1024 + jj)) * 256 + (k4 << 2));
    *(float4*)(wT + (((long)(dir * 64 + k4)) * 1024 + jj) * 4) = v;
}

// ---------- tiled f32 GEMM (proven round-3): out[m][n] = A . W[n] + bias ----------
template <int KDIM, bool GATHER>
__global__ __launch_bounds__(256) void gemm_xg(
    const float* __restrict__ A, const int* __restrict__ tokens,
    const float* __restrict__ W, const float* __restrict__ bias,
    float* __restrict__ out, int t_base, int t_sign)
{
    __shared__ float As[16][68];
    __shared__ float Bs[16][68];
    const int tid = threadIdx.x;
    const int m0 = blockIdx.x * 64;
    const int n0 = blockIdx.y * 64;

    const int lr = tid >> 2;
    const int lk = (tid & 3) * 4;
    const int mload = m0 + lr;
    const int tcc = mload & (TC - 1);
    const int b   = mload >> TCLOG;
    const int tglob = t_base + t_sign * tcc;
    const long arow = (long)b * SS + tglob;
    const float* Ap = GATHER ? (A + (long)tokens[arow] * KDIM + lk)
                             : (A + arow * (long)KDIM + lk);
    const float* Wp = W + (long)(n0 + lr) * KDIM + lk;

    const int tr = tid >> 4;
    const int tn = tid & 15;

    float acc[4][4];
    #pragma unroll
    for (int i = 0; i < 4; i++)
        #pragma unroll
        for (int j = 0; j < 4; j++) acc[i][j] = 0.f;

    #pragma unroll 1
    for (int k0 = 0; k0 < KDIM; k0 += 16) {
        float4 av = *(const float4*)(Ap + k0);
        float4 bv = *(const float4*)(Wp + k0);
        As[lk + 0][lr] = av.x; As[lk + 1][lr] = av.y;
        As[lk + 2][lr] = av.z; As[lk + 3][lr] = av.w;
        Bs[lk + 0][lr] = bv.x; Bs[lk + 1][lr] = bv.y;
        Bs[lk + 2][lr] = bv.z; Bs[lk + 3][lr] = bv.w;
        __syncthreads();
        #pragma unroll
        for (int kk = 0; kk < 16; kk++) {
            float a[4], w[4];
            *(float4*)a = *(const float4*)&As[kk][tr * 4];
            *(float4*)w = *(const float4*)&Bs[kk][tn * 4];
            #pragma unroll
            for (int i = 0; i < 4; i++)
                #pragma unroll
                for (int j = 0; j < 4; j++) acc[i][j] = fmaf(a[i], w[j], acc[i][j]);
        }
        __syncthreads();
    }

    float4 bc = *(const float4*)(bias + n0 + tn * 4);
    #pragma unroll
    for (int i = 0; i < 4; i++) {
        float4 r;
        r.x = acc[i][0] + bc.x; r.y = acc[i][1] + bc.y;
        r.z = acc[i][2] + bc.z; r.w = acc[i][3] + bc.w;
        *(float4*)(out + (long)(m0 + tr * 4 + i) * G4 + n0 + tn * 4) = r;
    }
}

// ---------- hybrid cached LSTM scan v3 (pinned VGPR cache) ----------
// Grid (64 batch, 2 dir), 1024 threads (16 waves = 4/SIMD).
// Thread j owns gate row j: 64 float4 weights.
//   k4 [0,KV)      -> VGPR, PINNED via empty asm (rematerialization-proof)
//   k4 [KV,KV+KL)  -> LDS  (144 KB, [kk][j] float4)
//   k4 [KV+KL,64)  -> streamed from L2 (656 KB/step)
__global__ __launch_bounds__(1024, 4) void lstm_cscan3(
    const float* __restrict__ xgF, const float* __restrict__ xgB, // [B][TC][1024]
    const float* __restrict__ wT,     // [2][64][1024][4]
    const float* __restrict__ bhh2,   // [2][1024]
    float* __restrict__ hout,         // [B*S][512]
    float* __restrict__ state,        // [2][B][2][256]
    int tbF, int tbB, int doInit)
{
    const int b = blockIdx.x;
    const int d = blockIdx.y;
    const int j = threadIdx.x;
    const float* xg  = (d ? xgB : xgF) + (long)b * TC * G4 + j;
    const float* wTd = wT + (long)d * 64 * G4 * 4;

    __shared__ float4 hl[2][64];        // 2 KB double-buffered h
    __shared__ float  gl[G4];           // 4 KB gate exchange
    __shared__ float4 lw[KL * 1024];    // 144 KB weight cache

    // ---- VGPR weight cache: k4 in [0,KV), pinned against remat ----
    float4 wv[KV];
    #pragma unroll
    for (int k4 = 0; k4 < KV; k4++) {
        wv[k4] = *(const float4*)(wTd + ((long)k4 * G4 + j) * 4);
        asm volatile("" : "+v"(wv[k4].x), "+v"(wv[k4].y),
                          "+v"(wv[k4].z), "+v"(wv[k4].w));
    }
    // ---- LDS weight cache: k4 in [KV,KV+KL) ----
    #pragma unroll
    for (int kk = 0; kk < KL; kk++)
        lw[kk * 1024 + j] = *(const float4*)(wTd + ((long)(KV + kk) * G4 + j) * 4);

    const float bj = bhh2[d * G4 + j];
    float c_reg = 0.f;
    if (doInit) {
        if (j < HH) ((float*)hl[0])[j] = 0.f;
    } else {
        if (j < HH) {
            ((float*)hl[0])[j] = state[((d * BB + b) * 2 + 0) * HH + j];
            c_reg               = state[((d * BB + b) * 2 + 1) * HH + j];
        }
    }
    __syncthreads();   // covers hl init + lw fill

    #pragma unroll 1
    for (int tc = 0; tc < TC; ++tc) {
        const int rb = tc & 1;
        const float4* hcur = hl[rb];
        float acc = xg[(long)tc * G4] + bj;

        // VGPR-pinned part
        #pragma unroll
        for (int k4 = 0; k4 < KV; k4++)
            acc = dot4(wv[k4], hcur[k4], acc);
        // LDS-cached part
        #pragma unroll
        for (int kk = 0; kk < KL; kk++)
            acc = dot4(lw[kk * 1024 + j], hcur[KV + kk], acc);
        // L2-streamed part
        #pragma unroll 5
        for (int k4 = KV + KL; k4 < 64; k4++) {
            float4 w = *(const float4*)(wTd + ((long)k4 * G4 + j) * 4);
            acc = dot4(w, hcur[k4], acc);
        }

        gl[j] = acc;
        __syncthreads();
        if (j < HH) {
            float gi = gl[j], gf = gl[j + 256], gg = gl[j + 512], go = gl[j + 768];
            c_reg = sigf(gf) * c_reg + sigf(gi) * tanhfast(gg);
            float h = sigf(go) * tanhfast(c_reg);
            ((float*)hl[rb ^ 1])[j] = h;
            const int t = d ? (tbB - tc) : (tbF + tc);
            hout[((long)(b * SS + t)) * 512 + d * HH + j] = h;
        }
        __syncthreads();
    }

    if (j < HH) {
        state[((d * BB + b) * 2 + 0) * HH + j] = ((float*)hl[TC & 1])[j];
        state[((d * BB + b) * 2 + 1) * HH + j] = c_reg;
    }
}

// ---------- emissions ----------
__global__ __launch_bounds__(256) void emissions_k(
    const float* __restrict__ h1, const float* __restrict__ clsw,
    const float* __restrict__ clsb, float* __restrict__ em)
{
    long u = (long)blockIdx.x * 256 + threadIdx.x;
    if (u >= (long)BB * SS * NC) return;
    int c = (int)(u % NC);
    long m = u / NC;
    const float4* hr = (const float4*)(h1 + m * 512);
    const float4* wr = (const float4*)(clsw + (long)c * 512);
    float s0 = 0, s1 = 0, s2 = 0, s3 = 0;
    #pragma unroll 8
    for (int q = 0; q < 128; q += 4) {
        float4 a0 = hr[q],     w0 = wr[q];
        float4 a1 = hr[q + 1], w1 = wr[q + 1];
        float4 a2 = hr[q + 2], w2 = wr[q + 2];
        float4 a3 = hr[q + 3], w3 = wr[q + 3];
        s0 += a0.x * w0.x + a0.y * w0.y + a0.z * w0.z + a0.w * w0.w;
        s1 += a1.x * w1.x + a1.y * w1.y + a1.z * w1.z + a1.w * w1.w;
        s2 += a2.x * w2.x + a2.y * w2.y + a2.z * w2.z + a2.w * w2.w;
        s3 += a3.x * w3.x + a3.y * w3.y + a3.z * w3.z + a3.w * w3.w;
    }
    em[u] = (s0 + s1) + (s2 + s3) + clsb[c];
}

// ---------- CRF log-likelihood per batch row ----------
__global__ __launch_bounds__(64) void crf_llh(
    const float* __restrict__ em, const int* __restrict__ labels,
    const int* __restrict__ mask, const float* __restrict__ start,
    const float* __restrict__ endt, const float* __restrict__ trans,
    float* __restrict__ llh)
{
    int b = blockIdx.x, j = threadIdx.x;
    bool act = j < NC;
    float tcol[NC];
    #pragma unroll
    for (int i = 0; i < NC; i++) tcol[i] = act ? trans[i * NC + j] : 0.f;
    const float* emb_ = em + (long)b * SS * NC;
    const int* lb = labels + b * SS;
    const int* mk = mask + b * SS;
    float alpha = act ? (start[j] + emb_[j]) : -1e30f;

    float num = 0.f;
    int msum = 0;
    for (int t = j; t < SS; t += 64) msum += (mk[t] != 0);
    for (int t = 1 + j; t < SS; t += 64) {
        float m = (float)mk[t];
        num += m * (trans[lb[t - 1] * NC + lb[t]] + emb_[t * NC + lb[t]]);
    }
    for (int o = 32; o > 0; o >>= 1) {
        num  += __shfl_down(num, o);
        msum += __shfl_down(msum, o);
    }
    msum = __shfl(msum, 0);

    for (int t = 1; t < SS; t++) {
        int m = mk[t];
        float emj = act ? emb_[t * NC + j] : 0.f;
        float v[NC];
        float mx = -1e30f;
        #pragma unroll
        for (int i = 0; i < NC; i++) {
            v[i] = __shfl(alpha, i) + tcol[i];
            mx = fmaxf(mx, v[i]);
        }
        float sum = 0.f;
        #pragma unroll
        for (int i = 0; i < NC; i++) sum += __expf(v[i] - mx);
        float nxt = mx + __logf(sum) + emj;
        if (m > 0 && act) alpha = nxt;
    }
    float fin = act ? alpha + endt[j] : -1e30f;
    float mx = -1e30f;
    #pragma unroll
    for (int i = 0; i < NC; i++) mx = fmaxf(mx, __shfl(fin, i));
    float s = 0.f;
    #pragma unroll
    for (int i = 0; i < NC; i++) s += __expf(__shfl(fin, i) - mx);
    float den = mx + __logf(s);
    if (j == 0) {
        int last_idx = msum - 1;
        float numer = num + start[lb[0]] + emb_[lb[0]] + endt[lb[last_idx]];
        llh[b] = numer - den;
    }
}

__global__ __launch_bounds__(64) void loss_k(const float* __restrict__ llh, float* __restrict__ out) {
    int j = threadIdx.x;
    float v = llh[j];
    for (int o = 32; o > 0; o >>= 1) v += __shfl_down(v, o);
    if (j == 0) out[0] = -v / 64.0f;
}

// ---------- Viterbi per batch row ----------
__global__ __launch_bounds__(64) void viterbi_k(
    const float* __restrict__ em, const int* __restrict__ mask,
    const float* __restrict__ start, const float* __restrict__ endt,
    const float* __restrict__ trans, float* __restrict__ outp)
{
    int b = blockIdx.x, j = threadIdx.x;
    bool act = j < NC;
    __shared__ unsigned char bp[SS][NC];
    float tcol[NC];
    #pragma unroll
    for (int i = 0; i < NC; i++) tcol[i] = act ? trans[i * NC + j] : 0.f;
    const float* emb_ = em + (long)b * SS * NC;
    const int* mk = mask + b * SS;
    float score = act ? (start[j] + emb_[j]) : -1e30f;

    for (int t = 1; t < SS; t++) {
        float best = 0.f;
        int bi = 0;
        #pragma unroll
        for (int i = 0; i < NC; i++) {
            float vv = __shfl(score, i) + tcol[i];
            if (i == 0 || vv > best) { best = vv; bi = i; }   // first-max (jnp.argmax)
        }
        int m = mk[t];
        float nxt = best + (act ? emb_[t * NC + j] : 0.f);
        if (act) {
            if (m > 0) { score = nxt; bp[t][j] = (unsigned char)bi; }
            else       { bp[t][j] = (unsigned char)j; }
        }
    }
    float fin = act ? score + endt[j] : -1e30f;
    float bestf = 0.f;
    int last = 0;
    #pragma unroll
    for (int i = 0; i < NC; i++) {
        float vv = __shfl(fin, i);
        if (i == 0 || vv > bestf) { bestf = vv; last = i; }
    }
    __syncthreads();
    if (j == 0) {
        int cur = last;
        outp[1 + (long)b * SS + (SS - 1)] = (float)cur;
        for (int t = SS - 1; t >= 1; t--) {
            cur = bp[t][cur];
            outp[1 + (long)b * SS + (t - 1)] = (float)cur;
        }
    }
}

extern "C" void kernel_launch(void* const* d_in, const int* in_sizes, int n_in,
                              void* d_out, int out_size, void* d_ws, size_t ws_size,
                              hipStream_t stream) {
    const int*   tok    = (const int*)d_in[0];
    const int*   lab    = (const int*)d_in[1];
    const int*   msk    = (const int*)d_in[2];
    const float* emb    = (const float*)d_in[3];
    const float* w_ih0  = (const float*)d_in[4];   // (2,1024,128)
    const float* w_hh0  = (const float*)d_in[5];   // (2,1024,256)
    const float* b_ih0  = (const float*)d_in[6];   // (2,1024)
    const float* b_hh0  = (const float*)d_in[7];
    const float* w_ih1  = (const float*)d_in[8];   // (2,1024,512)
    const float* w_hh1  = (const float*)d_in[9];
    const float* b_ih1  = (const float*)d_in[10];
    const float* b_hh1  = (const float*)d_in[11];
    const float* clsw   = (const float*)d_in[12];  // (9,512)
    const float* clsb   = (const float*)d_in[13];
    const float* startt = (const float*)d_in[14];
    const float* endt   = (const float*)d_in[15];
    const float* transm = (const float*)d_in[16];
    float* out = (float*)d_out;

    // ---- workspace carve (f32 elements); ~205 MB (round-3-proven footprint) ----
    size_t nH  = (size_t)BB * SS * 512;            // 16.78M each
    size_t nWT = (size_t)2 * 64 * 1024 * 4;        // 0.52M per layer
    size_t nEM = (size_t)BB * SS * NC;
    size_t nST = (size_t)2 * BB * 2 * HH;
    size_t nXG = (size_t)BB * TC * G4;             // 8.39M each dir

    float* H0  = (float*)d_ws;
    float* H1  = H0 + nH;
    float* WT0 = H1 + nH;
    float* WT1 = WT0 + nWT;
    float* EM  = WT1 + nWT;
    float* ST  = EM + nEM;
    float* LLH = ST + nST;
    float* XGF = LLH + 64;
    float* XGB = XGF + nXG;

    transpose_whh<<<512, 256, 0, stream>>>(w_hh0, WT0);
    transpose_whh<<<512, 256, 0, stream>>>(w_hh1, WT1);

    dim3 gg((BB * TC) / 64, G4 / 64);    // (128, 16)
    dim3 rg(BB, 2);                      // 128 blocks, 1024 threads

    // ---- layer 0 ----
    for (int c = 0; c < NCH; c++) {
        int tbF = c * TC;
        int tbB = SS - 1 - c * TC;
        gemm_xg<128, true><<<gg, 256, 0, stream>>>(emb, tok, w_ih0,              b_ih0,        XGF, tbF, +1);
        gemm_xg<128, true><<<gg, 256, 0, stream>>>(emb, tok, w_ih0 + 1024 * 128, b_ih0 + 1024, XGB, tbB, -1);
        lstm_cscan3<<<rg, 1024, 0, stream>>>(XGF, XGB, WT0, b_hh0, H0, ST, tbF, tbB, c == 0);
    }
    // ---- layer 1 ----
    for (int c = 0; c < NCH; c++) {
        int tbF = c * TC;
        int tbB = SS - 1 - c * TC;
        gemm_xg<512, false><<<gg, 256, 0, stream>>>(H0, nullptr, w_ih1,              b_ih1,        XGF, tbF, +1);
        gemm_xg<512, false><<<gg, 256, 0, stream>>>(H0, nullptr, w_ih1 + 1024 * 512, b_ih1 + 1024, XGB, tbB, -1);
        lstm_cscan3<<<rg, 1024, 0, stream>>>(XGF, XGB, WT1, b_hh1, H1, ST, tbF, tbB, c == 0);
    }

    emissions_k<<<((BB * SS * NC) + 255) / 256, 256, 0, stream>>>(H1, clsw, clsb, EM);
    crf_llh<<<BB, 64, 0, stream>>>(EM, lab, msk, startt, endt, transm, LLH);
    loss_k<<<1, 64, 0, stream>>>(LLH, out);
    viterbi_k<<<BB, 64, 0, stream>>>(EM, msk, startt, endt, transm, out);
}

// Round 10
// 7897.539 us; speedup vs baseline: 1.0152x; 1.0152x over previous
//
#include <hip/hip_runtime.h>
#include <math.h>

#define BB 64      // batch
#define SS 512     // seq len
#define EE 128     // embed dim
#define HH 256     // hidden
#define NC 9       // classes
#define G4 1024    // 4*H gates (one direction)
#define TCLOG 7
#define TC 128     // time chunk
#define NCH (SS / TC)

#define KV 16      // k4 chunks in VGPR: 2 rows x 16 f4 = 128 regs (cap 256 at 2 waves/SIMD)
#define KL 9       // k4 chunks in LDS = 144 KB
// streamed: k4 in [KV+KL, 64) = 39 chunks = 624 KB/step

// ---------- activations (overflow-safe, fast) ----------
__device__ __forceinline__ float sigf(float x) {
    return 1.0f / (1.0f + __expf(-x));
}
__device__ __forceinline__ float tanhfast(float x) {
    float a = fabsf(x);
    float e = __expf(-2.0f * a);
    float t = (1.0f - e) / (1.0f + e);
    return copysignf(t, x);
}
__device__ __forceinline__ float dot4(float4 w, float4 h, float a) {
    a = fmaf(w.x, h.x, a); a = fmaf(w.y, h.y, a);
    a = fmaf(w.z, h.z, a); a = fmaf(w.w, h.w, a);
    return a;
}

// ---------- transpose w_hh -> wT[dir][k4][j][4] ----------
__global__ void transpose_whh(const float* __restrict__ whh, float* __restrict__ wT) {
    // whh: [2][1024][256] ; wT: [2][64][1024][4]
    int idx = blockIdx.x * 256 + threadIdx.x;
    if (idx >= 2 * 64 * 1024) return;
    int jj  = idx & 1023;
    int k4  = (idx >> 10) & 63;
    int dir = idx >> 16;
    float4 v = *(const float4*)(whh + ((long)(dir * 1024 + jj)) * 256 + (k4 << 2));
    *(float4*)(wT + (((long)(dir * 64 + k4)) * 1024 + jj) * 4) = v;
}

// ---------- tiled f32 GEMM (proven round-3): out[m][n] = A . W[n] + bias ----------
template <int KDIM, bool GATHER>
__global__ __launch_bounds__(256) void gemm_xg(
    const float* __restrict__ A, const int* __restrict__ tokens,
    const float* __restrict__ W, const float* __restrict__ bias,
    float* __restrict__ out, int t_base, int t_sign)
{
    __shared__ float As[16][68];
    __shared__ float Bs[16][68];
    const int tid = threadIdx.x;
    const int m0 = blockIdx.x * 64;
    const int n0 = blockIdx.y * 64;

    const int lr = tid >> 2;
    const int lk = (tid & 3) * 4;
    const int mload = m0 + lr;
    const int tcc = mload & (TC - 1);
    const int b   = mload >> TCLOG;
    const int tglob = t_base + t_sign * tcc;
    const long arow = (long)b * SS + tglob;
    const float* Ap = GATHER ? (A + (long)tokens[arow] * KDIM + lk)
                             : (A + arow * (long)KDIM + lk);
    const float* Wp = W + (long)(n0 + lr) * KDIM + lk;

    const int tr = tid >> 4;
    const int tn = tid & 15;

    float acc[4][4];
    #pragma unroll
    for (int i = 0; i < 4; i++)
        #pragma unroll
        for (int j = 0; j < 4; j++) acc[i][j] = 0.f;

    #pragma unroll 1
    for (int k0 = 0; k0 < KDIM; k0 += 16) {
        float4 av = *(const float4*)(Ap + k0);
        float4 bv = *(const float4*)(Wp + k0);
        As[lk + 0][lr] = av.x; As[lk + 1][lr] = av.y;
        As[lk + 2][lr] = av.z; As[lk + 3][lr] = av.w;
        Bs[lk + 0][lr] = bv.x; Bs[lk + 1][lr] = bv.y;
        Bs[lk + 2][lr] = bv.z; Bs[lk + 3][lr] = bv.w;
        __syncthreads();
        #pragma unroll
        for (int kk = 0; kk < 16; kk++) {
            float a[4], w[4];
            *(float4*)a = *(const float4*)&As[kk][tr * 4];
            *(float4*)w = *(const float4*)&Bs[kk][tn * 4];
            #pragma unroll
            for (int i = 0; i < 4; i++)
                #pragma unroll
                for (int j = 0; j < 4; j++) acc[i][j] = fmaf(a[i], w[j], acc[i][j]);
        }
        __syncthreads();
    }

    float4 bc = *(const float4*)(bias + n0 + tn * 4);
    #pragma unroll
    for (int i = 0; i < 4; i++) {
        float4 r;
        r.x = acc[i][0] + bc.x; r.y = acc[i][1] + bc.y;
        r.z = acc[i][2] + bc.z; r.w = acc[i][3] + bc.w;
        *(float4*)(out + (long)(m0 + tr * 4 + i) * G4 + n0 + tn * 4) = r;
    }
}

// ---------- hybrid cached LSTM scan v4 (allocator-friendly VGPR cache) ----------
// Grid (64 batch, 2 dir), 512 threads (8 waves = 2/SIMD -> 256 VGPR cap).
// Thread t owns gate rows t and t+512 (2 rows): pressure ~200 < 256 -> no remat.
//   k4 [0,KV)      -> VGPR (2x16 float4 = 128 regs, 256 KB/CU)
//   k4 [KV,KV+KL)  -> LDS  (144 KB, [kk][row] float4)
//   k4 [KV+KL,64)  -> streamed from L2 (624 KB/step)
__global__ __launch_bounds__(512, 2) void lstm_vscan(
    const float* __restrict__ xgF, const float* __restrict__ xgB, // [B][TC][1024]
    const float* __restrict__ wT,     // [2][64][1024][4]
    const float* __restrict__ bhh2,   // [2][1024]
    float* __restrict__ hout,         // [B*S][512]
    float* __restrict__ state,        // [2][B][2][256]
    int tbF, int tbB, int doInit)
{
    const int b = blockIdx.x;
    const int d = blockIdx.y;
    const int t = threadIdx.x;              // 0..511
    const float* xg  = (d ? xgB : xgF) + (long)b * TC * G4;
    const float* wTd = wT + (long)d * 64 * G4 * 4;

    __shared__ float4 hl[2][64];        // 2 KB double-buffered h
    __shared__ float  gl[G4];           // 4 KB gate exchange
    __shared__ float4 lw[KL * 1024];    // 144 KB weight cache

    // ---- VGPR weight cache: rows t and t+512, k4 in [0,KV) ----
    float4 wv0[KV], wv1[KV];
    #pragma unroll
    for (int k4 = 0; k4 < KV; k4++) {
        wv0[k4] = *(const float4*)(wTd + ((long)k4 * G4 + t) * 4);
        wv1[k4] = *(const float4*)(wTd + ((long)k4 * G4 + t + 512) * 4);
    }
    // ---- LDS weight cache: k4 in [KV,KV+KL), both row halves ----
    #pragma unroll
    for (int kk = 0; kk < KL; kk++) {
        lw[kk * 1024 + t]       = *(const float4*)(wTd + ((long)(KV + kk) * G4 + t) * 4);
        lw[kk * 1024 + t + 512] = *(const float4*)(wTd + ((long)(KV + kk) * G4 + t + 512) * 4);
    }

    const float bj0 = bhh2[d * G4 + t];
    const float bj1 = bhh2[d * G4 + t + 512];
    float c_reg = 0.f;
    if (doInit) {
        if (t < HH) ((float*)hl[0])[t] = 0.f;
    } else {
        if (t < HH) {
            ((float*)hl[0])[t] = state[((d * BB + b) * 2 + 0) * HH + t];
            c_reg               = state[((d * BB + b) * 2 + 1) * HH + t];
        }
    }
    __syncthreads();   // covers hl init + lw fill

    #pragma unroll 1
    for (int tc = 0; tc < TC; ++tc) {
        const int rb = tc & 1;
        const float4* hcur = hl[rb];
        float acc0 = xg[(long)tc * G4 + t]       + bj0;
        float acc1 = xg[(long)tc * G4 + t + 512] + bj1;

        // VGPR-cached part
        #pragma unroll
        for (int k4 = 0; k4 < KV; k4++) {
            float4 h4 = hcur[k4];
            acc0 = dot4(wv0[k4], h4, acc0);
            acc1 = dot4(wv1[k4], h4, acc1);
        }
        // LDS-cached part (lane-consecutive float4: 2-way = free)
        #pragma unroll
        for (int kk = 0; kk < KL; kk++) {
            float4 h4 = hcur[KV + kk];
            acc0 = dot4(lw[kk * 1024 + t],       h4, acc0);
            acc1 = dot4(lw[kk * 1024 + t + 512], h4, acc1);
        }
        // L2-streamed part
        #pragma unroll 5
        for (int k4 = KV + KL; k4 < 64; k4++) {
            float4 h4 = hcur[k4];
            float4 w0 = *(const float4*)(wTd + ((long)k4 * G4 + t) * 4);
            float4 w1 = *(const float4*)(wTd + ((long)k4 * G4 + t + 512) * 4);
            acc0 = dot4(w0, h4, acc0);
            acc1 = dot4(w1, h4, acc1);
        }

        gl[t]       = acc0;    // rows 0..511   = i,f
        gl[t + 512] = acc1;    // rows 512..1023 = g,o
        __syncthreads();
        if (t < HH) {
            float gi = gl[t], gf = gl[t + 256], gg = gl[t + 512], go = gl[t + 768];
            c_reg = sigf(gf) * c_reg + sigf(gi) * tanhfast(gg);
            float h = sigf(go) * tanhfast(c_reg);
            ((float*)hl[rb ^ 1])[t] = h;
            const int tg = d ? (tbB - tc) : (tbF + tc);
            hout[((long)(b * SS + tg)) * 512 + d * HH + t] = h;
        }
        __syncthreads();
    }

    if (t < HH) {
        state[((d * BB + b) * 2 + 0) * HH + t] = ((float*)hl[TC & 1])[t];
        state[((d * BB + b) * 2 + 1) * HH + t] = c_reg;
    }
}

// ---------- emissions ----------
__global__ __launch_bounds__(256) void emissions_k(
    const float* __restrict__ h1, const float* __restrict__ clsw,
    const float* __restrict__ clsb, float* __restrict__ em)
{
    long u = (long)blockIdx.x * 256 + threadIdx.x;
    if (u >= (long)BB * SS * NC) return;
    int c = (int)(u % NC);
    long m = u / NC;
    const float4* hr = (const float4*)(h1 + m * 512);
    const float4* wr = (const float4*)(clsw + (long)c * 512);
    float s0 = 0, s1 = 0, s2 = 0, s3 = 0;
    #pragma unroll 8
    for (int q = 0; q < 128; q += 4) {
        float4 a0 = hr[q],     w0 = wr[q];
        float4 a1 = hr[q + 1], w1 = wr[q + 1];
        float4 a2 = hr[q + 2], w2 = wr[q + 2];
        float4 a3 = hr[q + 3], w3 = wr[q + 3];
        s0 += a0.x * w0.x + a0.y * w0.y + a0.z * w0.z + a0.w * w0.w;
        s1 += a1.x * w1.x + a1.y * w1.y + a1.z * w1.z + a1.w * w1.w;
        s2 += a2.x * w2.x + a2.y * w2.y + a2.z * w2.z + a2.w * w2.w;
        s3 += a3.x * w3.x + a3.y * w3.y + a3.z * w3.z + a3.w * w3.w;
    }
    em[u] = (s0 + s1) + (s2 + s3) + clsb[c];
}

// ---------- CRF log-likelihood per batch row ----------
__global__ __launch_bounds__(64) void crf_llh(
    const float* __restrict__ em, const int* __restrict__ labels,
    const int* __restrict__ mask, const float* __restrict__ start,
    const float* __restrict__ endt, const float* __restrict__ trans,
    float* __restrict__ llh)
{
    int b = blockIdx.x, j = threadIdx.x;
    bool act = j < NC;
    float tcol[NC];
    #pragma unroll
    for (int i = 0; i < NC; i++) tcol[i] = act ? trans[i * NC + j] : 0.f;
    const float* emb_ = em + (long)b * SS * NC;
    const int* lb = labels + b * SS;
    const int* mk = mask + b * SS;
    float alpha = act ? (start[j] + emb_[j]) : -1e30f;

    float num = 0.f;
    int msum = 0;
    for (int t = j; t < SS; t += 64) msum += (mk[t] != 0);
    for (int t = 1 + j; t < SS; t += 64) {
        float m = (float)mk[t];
        num += m * (trans[lb[t - 1] * NC + lb[t]] + emb_[t * NC + lb[t]]);
    }
    for (int o = 32; o > 0; o >>= 1) {
        num  += __shfl_down(num, o);
        msum += __shfl_down(msum, o);
    }
    msum = __shfl(msum, 0);

    for (int t = 1; t < SS; t++) {
        int m = mk[t];
        float emj = act ? emb_[t * NC + j] : 0.f;
        float v[NC];
        float mx = -1e30f;
        #pragma unroll
        for (int i = 0; i < NC; i++) {
            v[i] = __shfl(alpha, i) + tcol[i];
            mx = fmaxf(mx, v[i]);
        }
        float sum = 0.f;
        #pragma unroll
        for (int i = 0; i < NC; i++) sum += __expf(v[i] - mx);
        float nxt = mx + __logf(sum) + emj;
        if (m > 0 && act) alpha = nxt;
    }
    float fin = act ? alpha + endt[j] : -1e30f;
    float mx = -1e30f;
    #pragma unroll
    for (int i = 0; i < NC; i++) mx = fmaxf(mx, __shfl(fin, i));
    float s = 0.f;
    #pragma unroll
    for (int i = 0; i < NC; i++) s += __expf(__shfl(fin, i) - mx);
    float den = mx + __logf(s);
    if (j == 0) {
        int last_idx = msum - 1;
        float numer = num + start[lb[0]] + emb_[lb[0]] + endt[lb[last_idx]];
        llh[b] = numer - den;
    }
}

__global__ __launch_bounds__(64) void loss_k(const float* __restrict__ llh, float* __restrict__ out) {
    int j = threadIdx.x;
    float v = llh[j];
    for (int o = 32; o > 0; o >>= 1) v += __shfl_down(v, o);
    if (j == 0) out[0] = -v / 64.0f;
}

// ---------- Viterbi per batch row ----------
__global__ __launch_bounds__(64) void viterbi_k(
    const float* __restrict__ em, const int* __restrict__ mask,
    const float* __restrict__ start, const float* __restrict__ endt,
    const float* __restrict__ trans, float* __restrict__ outp)
{
    int b = blockIdx.x, j = threadIdx.x;
    bool act = j < NC;
    __shared__ unsigned char bp[SS][NC];
    float tcol[NC];
    #pragma unroll
    for (int i = 0; i < NC; i++) tcol[i] = act ? trans[i * NC + j] : 0.f;
    const float* emb_ = em + (long)b * SS * NC;
    const int* mk = mask + b * SS;
    float score = act ? (start[j] + emb_[j]) : -1e30f;

    for (int t = 1; t < SS; t++) {
        float best = 0.f;
        int bi = 0;
        #pragma unroll
        for (int i = 0; i < NC; i++) {
            float vv = __shfl(score, i) + tcol[i];
            if (i == 0 || vv > best) { best = vv; bi = i; }   // first-max (jnp.argmax)
        }
        int m = mk[t];
        float nxt = best + (act ? emb_[t * NC + j] : 0.f);
        if (act) {
            if (m > 0) { score = nxt; bp[t][j] = (unsigned char)bi; }
            else       { bp[t][j] = (unsigned char)j; }
        }
    }
    float fin = act ? score + endt[j] : -1e30f;
    float bestf = 0.f;
    int last = 0;
    #pragma unroll
    for (int i = 0; i < NC; i++) {
        float vv = __shfl(fin, i);
        if (i == 0 || vv > bestf) { bestf = vv; last = i; }
    }
    __syncthreads();
    if (j == 0) {
        int cur = last;
        outp[1 + (long)b * SS + (SS - 1)] = (float)cur;
        for (int t = SS - 1; t >= 1; t--) {
            cur = bp[t][cur];
            outp[1 + (long)b * SS + (t - 1)] = (float)cur;
        }
    }
}

extern "C" void kernel_launch(void* const* d_in, const int* in_sizes, int n_in,
                              void* d_out, int out_size, void* d_ws, size_t ws_size,
                              hipStream_t stream) {
    const int*   tok    = (const int*)d_in[0];
    const int*   lab    = (const int*)d_in[1];
    const int*   msk    = (const int*)d_in[2];
    const float* emb    = (const float*)d_in[3];
    const float* w_ih0  = (const float*)d_in[4];   // (2,1024,128)
    const float* w_hh0  = (const float*)d_in[5];   // (2,1024,256)
    const float* b_ih0  = (const float*)d_in[6];   // (2,1024)
    const float* b_hh0  = (const float*)d_in[7];
    const float* w_ih1  = (const float*)d_in[8];   // (2,1024,512)
    const float* w_hh1  = (const float*)d_in[9];
    const float* b_ih1  = (const float*)d_in[10];
    const float* b_hh1  = (const float*)d_in[11];
    const float* clsw   = (const float*)d_in[12];  // (9,512)
    const float* clsb   = (const float*)d_in[13];
    const float* startt = (const float*)d_in[14];
    const float* endt   = (const float*)d_in[15];
    const float* transm = (const float*)d_in[16];
    float* out = (float*)d_out;

    // ---- workspace carve (f32 elements); ~205 MB (round-3-proven footprint) ----
    size_t nH  = (size_t)BB * SS * 512;            // 16.78M each
    size_t nWT = (size_t)2 * 64 * 1024 * 4;        // 0.52M per layer
    size_t nEM = (size_t)BB * SS * NC;
    size_t nST = (size_t)2 * BB * 2 * HH;
    size_t nXG = (size_t)BB * TC * G4;             // 8.39M each dir

    float* H0  = (float*)d_ws;
    float* H1  = H0 + nH;
    float* WT0 = H1 + nH;
    float* WT1 = WT0 + nWT;
    float* EM  = WT1 + nWT;
    float* ST  = EM + nEM;
    float* LLH = ST + nST;
    float* XGF = LLH + 64;
    float* XGB = XGF + nXG;

    transpose_whh<<<512, 256, 0, stream>>>(w_hh0, WT0);
    transpose_whh<<<512, 256, 0, stream>>>(w_hh1, WT1);

    dim3 gg((BB * TC) / 64, G4 / 64);    // (128, 16)
    dim3 rg(BB, 2);                      // 128 blocks, 512 threads

    // ---- layer 0 ----
    for (int c = 0; c < NCH; c++) {
        int tbF = c * TC;
        int tbB = SS - 1 - c * TC;
        gemm_xg<128, true><<<gg, 256, 0, stream>>>(emb, tok, w_ih0,              b_ih0,        XGF, tbF, +1);
        gemm_xg<128, true><<<gg, 256, 0, stream>>>(emb, tok, w_ih0 + 1024 * 128, b_ih0 + 1024, XGB, tbB, -1);
        lstm_vscan<<<rg, 512, 0, stream>>>(XGF, XGB, WT0, b_hh0, H0, ST, tbF, tbB, c == 0);
    }
    // ---- layer 1 ----
    for (int c = 0; c < NCH; c++) {
        int tbF = c * TC;
        int tbB = SS - 1 - c * TC;
        gemm_xg<512, false><<<gg, 256, 0, stream>>>(H0, nullptr, w_ih1,              b_ih1,        XGF, tbF, +1);
        gemm_xg<512, false><<<gg, 256, 0, stream>>>(H0, nullptr, w_ih1 + 1024 * 512, b_ih1 + 1024, XGB, tbB, -1);
        lstm_vscan<<<rg, 512, 0, stream>>>(XGF, XGB, WT1, b_hh1, H1, ST, tbF, tbB, c == 0);
    }

    emissions_k<<<((BB * SS * NC) + 255) / 256, 256, 0, stream>>>(H1, clsw, clsb, EM);
    crf_llh<<<BB, 64, 0, stream>>>(EM, lab, msk, startt, endt, transm, LLH);
    loss_k<<<1, 64, 0, stream>>>(LLH, out);
    viterbi_k<<<BB, 64, 0, stream>>>(EM, msk, startt, endt, transm, out);
}

// Round 11
// 7840.968 us; speedup vs baseline: 1.0225x; 1.0072x over previous
//
#include <hip/hip_runtime.h>
#include <math.h>

#define BB 64      // batch
#define SS 512     // seq len
#define EE 128     // embed dim
#define HH 256     // hidden
#define NC 9       // classes
#define G4 1024    // 4*H gates (one direction)
#define TCLOG 7
#define TC 128     // time chunk
#define NCH (SS / TC)

#define KV 16      // k4 chunks in VGPR: 2 rows x 16 f4 = 128 regs, PINNED (cap 256)
#define KL 9       // k4 chunks in LDS = 144 KB
// streamed: k4 in [KV+KL, 64) = 39 chunks = 624 KB/step

// ---------- activations (overflow-safe, fast) ----------
__device__ __forceinline__ float sigf(float x) {
    return 1.0f / (1.0f + __expf(-x));
}
__device__ __forceinline__ float tanhfast(float x) {
    float a = fabsf(x);
    float e = __expf(-2.0f * a);
    float t = (1.0f - e) / (1.0f + e);
    return copysignf(t, x);
}
__device__ __forceinline__ float dot4(float4 w, float4 h, float a) {
    a = fmaf(w.x, h.x, a); a = fmaf(w.y, h.y, a);
    a = fmaf(w.z, h.z, a); a = fmaf(w.w, h.w, a);
    return a;
}
#define PIN4(v) asm volatile("" : "+v"((v).x), "+v"((v).y), "+v"((v).z), "+v"((v).w))

// ---------- transpose w_hh -> wT[dir][k4][j][4] ----------
__global__ void transpose_whh(const float* __restrict__ whh, float* __restrict__ wT) {
    // whh: [2][1024][256] ; wT: [2][64][1024][4]
    int idx = blockIdx.x * 256 + threadIdx.x;
    if (idx >= 2 * 64 * 1024) return;
    int jj  = idx & 1023;
    int k4  = (idx >> 10) & 63;
    int dir = idx >> 16;
    float4 v = *(const float4*)(whh + ((long)(dir * 1024 + jj)) * 256 + (k4 << 2));
    *(float4*)(wT + (((long)(dir * 64 + k4)) * 1024 + jj) * 4) = v;
}

// ---------- tiled f32 GEMM (proven round-3): out[m][n] = A . W[n] + bias ----------
template <int KDIM, bool GATHER>
__global__ __launch_bounds__(256) void gemm_xg(
    const float* __restrict__ A, const int* __restrict__ tokens,
    const float* __restrict__ W, const float* __restrict__ bias,
    float* __restrict__ out, int t_base, int t_sign)
{
    __shared__ float As[16][68];
    __shared__ float Bs[16][68];
    const int tid = threadIdx.x;
    const int m0 = blockIdx.x * 64;
    const int n0 = blockIdx.y * 64;

    const int lr = tid >> 2;
    const int lk = (tid & 3) * 4;
    const int mload = m0 + lr;
    const int tcc = mload & (TC - 1);
    const int b   = mload >> TCLOG;
    const int tglob = t_base + t_sign * tcc;
    const long arow = (long)b * SS + tglob;
    const float* Ap = GATHER ? (A + (long)tokens[arow] * KDIM + lk)
                             : (A + arow * (long)KDIM + lk);
    const float* Wp = W + (long)(n0 + lr) * KDIM + lk;

    const int tr = tid >> 4;
    const int tn = tid & 15;

    float acc[4][4];
    #pragma unroll
    for (int i = 0; i < 4; i++)
        #pragma unroll
        for (int j = 0; j < 4; j++) acc[i][j] = 0.f;

    #pragma unroll 1
    for (int k0 = 0; k0 < KDIM; k0 += 16) {
        float4 av = *(const float4*)(Ap + k0);
        float4 bv = *(const float4*)(Wp + k0);
        As[lk + 0][lr] = av.x; As[lk + 1][lr] = av.y;
        As[lk + 2][lr] = av.z; As[lk + 3][lr] = av.w;
        Bs[lk + 0][lr] = bv.x; Bs[lk + 1][lr] = bv.y;
        Bs[lk + 2][lr] = bv.z; Bs[lk + 3][lr] = bv.w;
        __syncthreads();
        #pragma unroll
        for (int kk = 0; kk < 16; kk++) {
            float a[4], w[4];
            *(float4*)a = *(const float4*)&As[kk][tr * 4];
            *(float4*)w = *(const float4*)&Bs[kk][tn * 4];
            #pragma unroll
            for (int i = 0; i < 4; i++)
                #pragma unroll
                for (int j = 0; j < 4; j++) acc[i][j] = fmaf(a[i], w[j], acc[i][j]);
        }
        __syncthreads();
    }

    float4 bc = *(const float4*)(bias + n0 + tn * 4);
    #pragma unroll
    for (int i = 0; i < 4; i++) {
        float4 r;
        r.x = acc[i][0] + bc.x; r.y = acc[i][1] + bc.y;
        r.z = acc[i][2] + bc.z; r.w = acc[i][3] + bc.w;
        *(float4*)(out + (long)(m0 + tr * 4 + i) * G4 + n0 + tn * 4) = r;
    }
}

// ---------- hybrid cached LSTM scan v5 (pinned cache + 256-reg cap) ----------
// Grid (64 batch, 2 dir), 512 threads (8 waves = 2/SIMD -> 256 VGPR cap).
// Thread t owns gate rows t and t+512. KV chunks pinned in VGPR via asm
// (remat-illegal); pressure ~200 < 256 cap -> no scratch.
//   k4 [0,KV)      -> VGPR pinned (128 regs, 256 KB/CU)
//   k4 [KV,KV+KL)  -> LDS (144 KB)
//   k4 [KV+KL,64)  -> streamed from L2 (624 KB/step)
__global__ __launch_bounds__(512, 2) void lstm_vscan(
    const float* __restrict__ xgF, const float* __restrict__ xgB, // [B][TC][1024]
    const float* __restrict__ wT,     // [2][64][1024][4]
    const float* __restrict__ bhh2,   // [2][1024]
    float* __restrict__ hout,         // [B*S][512]
    float* __restrict__ state,        // [2][B][2][256]
    int tbF, int tbB, int doInit)
{
    const int b = blockIdx.x;
    const int d = blockIdx.y;
    const int t = threadIdx.x;              // 0..511
    const float* xg  = (d ? xgB : xgF) + (long)b * TC * G4;
    const float* wTd = wT + (long)d * 64 * G4 * 4;

    __shared__ float4 hl[2][64];        // 2 KB double-buffered h
    __shared__ float  gl[G4];           // 4 KB gate exchange
    __shared__ float4 lw[KL * 1024];    // 144 KB weight cache

    // ---- VGPR weight cache: rows t and t+512, k4 in [0,KV), PINNED ----
    float4 wv0[KV], wv1[KV];
    #pragma unroll
    for (int k4 = 0; k4 < KV; k4++) {
        wv0[k4] = *(const float4*)(wTd + ((long)k4 * G4 + t) * 4);
        wv1[k4] = *(const float4*)(wTd + ((long)k4 * G4 + t + 512) * 4);
        PIN4(wv0[k4]);
        PIN4(wv1[k4]);
    }
    // ---- LDS weight cache: k4 in [KV,KV+KL), both row halves ----
    #pragma unroll
    for (int kk = 0; kk < KL; kk++) {
        lw[kk * 1024 + t]       = *(const float4*)(wTd + ((long)(KV + kk) * G4 + t) * 4);
        lw[kk * 1024 + t + 512] = *(const float4*)(wTd + ((long)(KV + kk) * G4 + t + 512) * 4);
    }

    const float bj0 = bhh2[d * G4 + t];
    const float bj1 = bhh2[d * G4 + t + 512];
    float c_reg = 0.f;
    if (doInit) {
        if (t < HH) ((float*)hl[0])[t] = 0.f;
    } else {
        if (t < HH) {
            ((float*)hl[0])[t] = state[((d * BB + b) * 2 + 0) * HH + t];
            c_reg               = state[((d * BB + b) * 2 + 1) * HH + t];
        }
    }
    __syncthreads();   // covers hl init + lw fill

    #pragma unroll 1
    for (int tc = 0; tc < TC; ++tc) {
        const int rb = tc & 1;
        const float4* hcur = hl[rb];
        float acc0 = xg[(long)tc * G4 + t]       + bj0;
        float acc1 = xg[(long)tc * G4 + t + 512] + bj1;

        // VGPR-pinned part
        #pragma unroll
        for (int k4 = 0; k4 < KV; k4++) {
            float4 h4 = hcur[k4];
            acc0 = dot4(wv0[k4], h4, acc0);
            acc1 = dot4(wv1[k4], h4, acc1);
        }
        // LDS-cached part (lane-consecutive float4: 2-way = free)
        #pragma unroll
        for (int kk = 0; kk < KL; kk++) {
            float4 h4 = hcur[KV + kk];
            acc0 = dot4(lw[kk * 1024 + t],       h4, acc0);
            acc1 = dot4(lw[kk * 1024 + t + 512], h4, acc1);
        }
        // L2-streamed part
        #pragma unroll 5
        for (int k4 = KV + KL; k4 < 64; k4++) {
            float4 h4 = hcur[k4];
            float4 w0 = *(const float4*)(wTd + ((long)k4 * G4 + t) * 4);
            float4 w1 = *(const float4*)(wTd + ((long)k4 * G4 + t + 512) * 4);
            acc0 = dot4(w0, h4, acc0);
            acc1 = dot4(w1, h4, acc1);
        }

        gl[t]       = acc0;    // rows 0..511   = i,f
        gl[t + 512] = acc1;    // rows 512..1023 = g,o
        __syncthreads();
        if (t < HH) {
            float gi = gl[t], gf = gl[t + 256], gg = gl[t + 512], go = gl[t + 768];
            c_reg = sigf(gf) * c_reg + sigf(gi) * tanhfast(gg);
            float h = sigf(go) * tanhfast(c_reg);
            ((float*)hl[rb ^ 1])[t] = h;
            const int tg = d ? (tbB - tc) : (tbF + tc);
            hout[((long)(b * SS + tg)) * 512 + d * HH + t] = h;
        }
        __syncthreads();
    }

    if (t < HH) {
        state[((d * BB + b) * 2 + 0) * HH + t] = ((float*)hl[TC & 1])[t];
        state[((d * BB + b) * 2 + 1) * HH + t] = c_reg;
    }
}

// ---------- emissions ----------
__global__ __launch_bounds__(256) void emissions_k(
    const float* __restrict__ h1, const float* __restrict__ clsw,
    const float* __restrict__ clsb, float* __restrict__ em)
{
    long u = (long)blockIdx.x * 256 + threadIdx.x;
    if (u >= (long)BB * SS * NC) return;
    int c = (int)(u % NC);
    long m = u / NC;
    const float4* hr = (const float4*)(h1 + m * 512);
    const float4* wr = (const float4*)(clsw + (long)c * 512);
    float s0 = 0, s1 = 0, s2 = 0, s3 = 0;
    #pragma unroll 8
    for (int q = 0; q < 128; q += 4) {
        float4 a0 = hr[q],     w0 = wr[q];
        float4 a1 = hr[q + 1], w1 = wr[q + 1];
        float4 a2 = hr[q + 2], w2 = wr[q + 2];
        float4 a3 = hr[q + 3], w3 = wr[q + 3];
        s0 += a0.x * w0.x + a0.y * w0.y + a0.z * w0.z + a0.w * w0.w;
        s1 += a1.x * w1.x + a1.y * w1.y + a1.z * w1.z + a1.w * w1.w;
        s2 += a2.x * w2.x + a2.y * w2.y + a2.z * w2.z + a2.w * w2.w;
        s3 += a3.x * w3.x + a3.y * w3.y + a3.z * w3.z + a3.w * w3.w;
    }
    em[u] = (s0 + s1) + (s2 + s3) + clsb[c];
}

// ---------- CRF log-likelihood per batch row ----------
__global__ __launch_bounds__(64) void crf_llh(
    const float* __restrict__ em, const int* __restrict__ labels,
    const int* __restrict__ mask, const float* __restrict__ start,
    const float* __restrict__ endt, const float* __restrict__ trans,
    float* __restrict__ llh)
{
    int b = blockIdx.x, j = threadIdx.x;
    bool act = j < NC;
    float tcol[NC];
    #pragma unroll
    for (int i = 0; i < NC; i++) tcol[i] = act ? trans[i * NC + j] : 0.f;
    const float* emb_ = em + (long)b * SS * NC;
    const int* lb = labels + b * SS;
    const int* mk = mask + b * SS;
    float alpha = act ? (start[j] + emb_[j]) : -1e30f;

    float num = 0.f;
    int msum = 0;
    for (int t = j; t < SS; t += 64) msum += (mk[t] != 0);
    for (int t = 1 + j; t < SS; t += 64) {
        float m = (float)mk[t];
        num += m * (trans[lb[t - 1] * NC + lb[t]] + emb_[t * NC + lb[t]]);
    }
    for (int o = 32; o > 0; o >>= 1) {
        num  += __shfl_down(num, o);
        msum += __shfl_down(msum, o);
    }
    msum = __shfl(msum, 0);

    for (int t = 1; t < SS; t++) {
        int m = mk[t];
        float emj = act ? emb_[t * NC + j] : 0.f;
        float v[NC];
        float mx = -1e30f;
        #pragma unroll
        for (int i = 0; i < NC; i++) {
            v[i] = __shfl(alpha, i) + tcol[i];
            mx = fmaxf(mx, v[i]);
        }
        float sum = 0.f;
        #pragma unroll
        for (int i = 0; i < NC; i++) sum += __expf(v[i] - mx);
        float nxt = mx + __logf(sum) + emj;
        if (m > 0 && act) alpha = nxt;
    }
    float fin = act ? alpha + endt[j] : -1e30f;
    float mx = -1e30f;
    #pragma unroll
    for (int i = 0; i < NC; i++) mx = fmaxf(mx, __shfl(fin, i));
    float s = 0.f;
    #pragma unroll
    for (int i = 0; i < NC; i++) s += __expf(__shfl(fin, i) - mx);
    float den = mx + __logf(s);
    if (j == 0) {
        int last_idx = msum - 1;
        float numer = num + start[lb[0]] + emb_[lb[0]] + endt[lb[last_idx]];
        llh[b] = numer - den;
    }
}

__global__ __launch_bounds__(64) void loss_k(const float* __restrict__ llh, float* __restrict__ out) {
    int j = threadIdx.x;
    float v = llh[j];
    for (int o = 32; o > 0; o >>= 1) v += __shfl_down(v, o);
    if (j == 0) out[0] = -v / 64.0f;
}

// ---------- Viterbi per batch row ----------
__global__ __launch_bounds__(64) void viterbi_k(
    const float* __restrict__ em, const int* __restrict__ mask,
    const float* __restrict__ start, const float* __restrict__ endt,
    const float* __restrict__ trans, float* __restrict__ outp)
{
    int b = blockIdx.x, j = threadIdx.x;
    bool act = j < NC;
    __shared__ unsigned char bp[SS][NC];
    float tcol[NC];
    #pragma unroll
    for (int i = 0; i < NC; i++) tcol[i] = act ? trans[i * NC + j] : 0.f;
    const float* emb_ = em + (long)b * SS * NC;
    const int* mk = mask + b * SS;
    float score = act ? (start[j] + emb_[j]) : -1e30f;

    for (int t = 1; t < SS; t++) {
        float best = 0.f;
        int bi = 0;
        #pragma unroll
        for (int i = 0; i < NC; i++) {
            float vv = __shfl(score, i) + tcol[i];
            if (i == 0 || vv > best) { best = vv; bi = i; }   // first-max (jnp.argmax)
        }
        int m = mk[t];
        float nxt = best + (act ? emb_[t * NC + j] : 0.f);
        if (act) {
            if (m > 0) { score = nxt; bp[t][j] = (unsigned char)bi; }
            else       { bp[t][j] = (unsigned char)j; }
        }
    }
    float fin = act ? score + endt[j] : -1e30f;
    float bestf = 0.f;
    int last = 0;
    #pragma unroll
    for (int i = 0; i < NC; i++) {
        float vv = __shfl(fin, i);
        if (i == 0 || vv > bestf) { bestf = vv; last = i; }
    }
    __syncthreads();
    if (j == 0) {
        int cur = last;
        outp[1 + (long)b * SS + (SS - 1)] = (float)cur;
        for (int t = SS - 1; t >= 1; t--) {
            cur = bp[t][cur];
            outp[1 + (long)b * SS + (t - 1)] = (float)cur;
        }
    }
}

extern "C" void kernel_launch(void* const* d_in, const int* in_sizes, int n_in,
                              void* d_out, int out_size, void* d_ws, size_t ws_size,
                              hipStream_t stream) {
    const int*   tok    = (const int*)d_in[0];
    const int*   lab    = (const int*)d_in[1];
    const int*   msk    = (const int*)d_in[2];
    const float* emb    = (const float*)d_in[3];
    const float* w_ih0  = (const float*)d_in[4];   // (2,1024,128)
    const float* w_hh0  = (const float*)d_in[5];   // (2,1024,256)
    const float* b_ih0  = (const float*)d_in[6];   // (2,1024)
    const float* b_hh0  = (const float*)d_in[7];
    const float* w_ih1  = (const float*)d_in[8];   // (2,1024,512)
    const float* w_hh1  = (const float*)d_in[9];
    const float* b_ih1  = (const float*)d_in[10];
    const float* b_hh1  = (const float*)d_in[11];
    const float* clsw   = (const float*)d_in[12];  // (9,512)
    const float* clsb   = (const float*)d_in[13];
    const float* startt = (const float*)d_in[14];
    const float* endt   = (const float*)d_in[15];
    const float* transm = (const float*)d_in[16];
    float* out = (float*)d_out;

    // ---- workspace carve (f32 elements); ~205 MB (round-3-proven footprint) ----
    size_t nH  = (size_t)BB * SS * 512;            // 16.78M each
    size_t nWT = (size_t)2 * 64 * 1024 * 4;        // 0.52M per layer
    size_t nEM = (size_t)BB * SS * NC;
    size_t nST = (size_t)2 * BB * 2 * HH;
    size_t nXG = (size_t)BB * TC * G4;             // 8.39M each dir

    float* H0  = (float*)d_ws;
    float* H1  = H0 + nH;
    float* WT0 = H1 + nH;
    float* WT1 = WT0 + nWT;
    float* EM  = WT1 + nWT;
    float* ST  = EM + nEM;
    float* LLH = ST + nST;
    float* XGF = LLH + 64;
    float* XGB = XGF + nXG;

    transpose_whh<<<512, 256, 0, stream>>>(w_hh0, WT0);
    transpose_whh<<<512, 256, 0, stream>>>(w_hh1, WT1);

    dim3 gg((BB * TC) / 64, G4 / 64);    // (128, 16)
    dim3 rg(BB, 2);                      // 128 blocks, 512 threads

    // ---- layer 0 ----
    for (int c = 0; c < NCH; c++) {
        int tbF = c * TC;
        int tbB = SS - 1 - c * TC;
        gemm_xg<128, true><<<gg, 256, 0, stream>>>(emb, tok, w_ih0,              b_ih0,        XGF, tbF, +1);
        gemm_xg<128, true><<<gg, 256, 0, stream>>>(emb, tok, w_ih0 + 1024 * 128, b_ih0 + 1024, XGB, tbB, -1);
        lstm_vscan<<<rg, 512, 0, stream>>>(XGF, XGB, WT0, b_hh0, H0, ST, tbF, tbB, c == 0);
    }
    // ---- layer 1 ----
    for (int c = 0; c < NCH; c++) {
        int tbF = c * TC;
        int tbB = SS - 1 - c * TC;
        gemm_xg<512, false><<<gg, 256, 0, stream>>>(H0, nullptr, w_ih1,              b_ih1,        XGF, tbF, +1);
        gemm_xg<512, false><<<gg, 256, 0, stream>>>(H0, nullptr, w_ih1 + 1024 * 512, b_ih1 + 1024, XGB, tbB, -1);
        lstm_vscan<<<rg, 512, 0, stream>>>(XGF, XGB, WT1, b_hh1, H1, ST, tbF, tbB, c == 0);
    }

    emissions_k<<<((BB * SS * NC) + 255) / 256, 256, 0, stream>>>(H1, clsw, clsb, EM);
    crf_llh<<<BB, 64, 0, stream>>>(EM, lab, msk, startt, endt, transm, LLH);
    loss_k<<<1, 64, 0, stream>>>(LLH, out);
    viterbi_k<<<BB, 64, 0, stream>>>(EM, msk, startt, endt, transm, out);
}